// Round 1
// baseline (3266.972 us; speedup 1.0000x reference)
//
#include <hip/hip_runtime.h>

#define TAGS 64
#define MAXT 512
#define NEG -10000.0f

// One wave (64 threads) per batch element. lane = "next" tag.
// Forward: fv[next] = max_prev(fv[prev] + W[next,prev]) + feat[t,next], t < len only
//   (past len, reference freezes fv and uses identity backpointers, so the
//    backtrace emits best_last for all t >= len-1 — no work needed).
// Backpointers kept entirely in LDS (T*K u8 = 32 KB) so the serial backtrace
// chase is LDS-latency, not HBM-latency.
__global__ __launch_bounds__(64, 1) void crf_viterbi(
    const float* __restrict__ feats,   // [B, T, K]
    const float* __restrict__ weights, // [K, K]  (weights[next][prev])
    const int*   __restrict__ lens,    // [B]
    float*       __restrict__ out,     // [B] scores ++ [B*T] paths (as float)
    int B, int T)
{
    const int b    = blockIdx.x;
    const int lane = threadIdx.x;              // next tag
    const int len  = lens[b];                  // 1..T

    __shared__ float fv[TAGS];
    __shared__ float term[TAGS];
    __shared__ unsigned char  bptr[MAXT * TAGS];
    __shared__ unsigned short path[MAXT];
    __shared__ int s_bestlast;

    // W row for this lane -> 64 VGPRs, reused every step
    float w[TAGS];
    #pragma unroll
    for (int i = 0; i < TAGS / 4; ++i) {
        const float4 v = *reinterpret_cast<const float4*>(weights + lane * TAGS + i * 4);
        w[4*i+0] = v.x; w[4*i+1] = v.y; w[4*i+2] = v.z; w[4*i+3] = v.w;
    }

    fv[lane] = (lane == 0) ? 0.0f : NEG;       // START = 0
    __syncthreads();

    const float* fb = feats + (size_t)b * T * TAGS;
    float feat_cur = fb[lane];                 // t = 0 (len >= 1 guaranteed)

    #pragma unroll 1
    for (int t = 0; t < len; ++t) {
        // prefetch next step's emission
        float feat_next = 0.0f;
        if (t + 1 < len) feat_next = fb[(size_t)(t + 1) * TAGS + lane];

        // broadcast fv from LDS (same-address b128 reads = conflict-free)
        float f[TAGS];
        #pragma unroll
        for (int i = 0; i < TAGS / 4; ++i) {
            const float4 v = *reinterpret_cast<const float4*>(&fv[i * 4]);
            f[4*i+0] = v.x; f[4*i+1] = v.y; f[4*i+2] = v.z; f[4*i+3] = v.w;
        }

        float c[TAGS];
        #pragma unroll
        for (int p = 0; p < TAGS; ++p) c[p] = f[p] + w[p];

        // pairwise argmax tree; strict '>' with lower-index side first
        // == numpy argmax first-occurrence tie-break, exact float compare
        float bv[32]; int bi[32];
        #pragma unroll
        for (int k = 0; k < 32; ++k) {
            const bool g = c[2*k+1] > c[2*k];
            bv[k] = g ? c[2*k+1] : c[2*k];
            bi[k] = g ? (2*k+1) : (2*k);
        }
        #pragma unroll
        for (int n = 16; n >= 1; n >>= 1) {
            #pragma unroll
            for (int k = 0; k < n; ++k) {
                const bool g = bv[2*k+1] > bv[2*k];
                bv[k] = g ? bv[2*k+1] : bv[2*k];
                bi[k] = g ? bi[2*k+1] : bi[2*k];
            }
        }

        const float nf = bv[0] + feat_cur;     // emission added after max
        bptr[t * TAGS + lane] = (unsigned char)bi[0];
        fv[lane] = nf;
        __syncthreads();                       // single-wave block: cheap
        feat_cur = feat_next;
    }

    // terminal = fv + weights[END=1][prev]
    term[lane] = fv[lane] + weights[1 * TAGS + lane];
    __syncthreads();

    if (lane == 0) {
        float best = term[0]; int bidx = 0;
        for (int p = 1; p < TAGS; ++p) {
            if (term[p] > best) { best = term[p]; bidx = p; }   // first-max wins
        }
        out[b] = best;
        s_bestlast = bidx;
    }
    __syncthreads();
    const int bestlast = s_bestlast;

    // padding region: path[t] = bestlast for t in [len-1, T)
    for (int t = lane; t < T; t += 64)
        if (t >= len - 1) path[t] = (unsigned short)bestlast;

    // serial chase (lane 0, LDS-resident backpointers)
    if (lane == 0) {
        int tag = bestlast;
        for (int t = len - 1; t >= 1; --t) {
            tag = bptr[t * TAGS + tag];
            path[t - 1] = (unsigned short)tag;
        }
    }
    __syncthreads();

    // coalesced path writeback (tags as float32)
    float* pout = out + B + (size_t)b * T;
    for (int t = lane; t < T; t += 64)
        pout[t] = (float)path[t];
}

extern "C" void kernel_launch(void* const* d_in, const int* in_sizes, int n_in,
                              void* d_out, int out_size, void* d_ws, size_t ws_size,
                              hipStream_t stream) {
    const float* feats   = (const float*)d_in[0];
    const float* weights = (const float*)d_in[1];
    const int*   lens    = (const int*)d_in[2];
    float*       out     = (float*)d_out;

    const int B = in_sizes[2];
    const int T = in_sizes[0] / (B * TAGS);

    crf_viterbi<<<dim3(B), dim3(64), 0, stream>>>(feats, weights, lens, out, B, T);
}

// Round 2
// 1001.166 us; speedup vs baseline: 3.2632x; 3.2632x over previous
//
#include <hip/hip_runtime.h>

#define TAGS 64
#define MAXT 512
#define NEG  -10000.0f
#define PF   8

// One wave (64 lanes) per batch. lane = "next" tag. SINGLE-WAVE BLOCK:
// no __syncthreads anywhere — same-wave DS ops are processed in program
// order, so fv write -> fv read needs no barrier. This removes the per-step
// `s_waitcnt vmcnt(0) lgkmcnt(0)` + s_barrier the compiler emits for
// __syncthreads, which serialized the feat prefetch every step (round-1
// profile: VALUBusy 25%, 14.7K cyc/step with only ~560 issue cycles of work).
__global__ __launch_bounds__(64, 1) void crf_viterbi(
    const float* __restrict__ feats,   // [B, T, K]
    const float* __restrict__ weights, // [K, K] (weights[next][prev])
    const int*   __restrict__ lens,    // [B]
    float*       __restrict__ out,     // [B] scores ++ [B*T] paths (as f32)
    int B, int T)
{
    const int b    = blockIdx.x;
    const int lane = threadIdx.x;              // next tag
    const int len  = lens[b];                  // 1..T

    __shared__ float fv[TAGS];
    __shared__ unsigned char  bptr[MAXT * TAGS];
    __shared__ unsigned short path[MAXT];

    // W row for this lane -> 64 VGPRs, reused every step
    float w[TAGS];
    #pragma unroll
    for (int i = 0; i < 16; ++i) {
        const float4 v = *reinterpret_cast<const float4*>(weights + lane * TAGS + i * 4);
        w[4*i+0] = v.x; w[4*i+1] = v.y; w[4*i+2] = v.z; w[4*i+3] = v.w;
    }
    const float wEnd = weights[1 * TAGS + lane];  // transition into END tag

    fv[lane] = (lane == 0) ? 0.0f : NEG;          // START = 0
    __builtin_amdgcn_wave_barrier();

    const float* fb = feats + (size_t)b * T * TAGS;

    // deep feat prefetch: PF steps in flight, double-buffered per chunk
    float cur[PF];
    #pragma unroll
    for (int i = 0; i < PF; ++i) {
        int ti = (i < len) ? i : (len - 1);       // clamp: always a valid addr
        cur[i] = fb[(size_t)ti * TAGS + lane];
    }

    float nf = NEG;   // this lane's running fv value (len >= 1 guaranteed)

    for (int t0 = 0; t0 < len; t0 += PF) {
        // issue next chunk's loads before computing on current chunk
        float nxt[PF];
        #pragma unroll
        for (int i = 0; i < PF; ++i) {
            int ti = t0 + PF + i;
            ti = (ti < len) ? ti : (len - 1);
            nxt[i] = fb[(size_t)ti * TAGS + lane];
        }
        const int cnt = len - t0;                 // >= 1
        #pragma unroll
        for (int i = 0; i < PF; ++i) {
            if (i < cnt) {                        // wave-uniform branch
                const int t = t0 + i;
                // grouped add+argmax over 64 prev tags (4 at a time, then
                // a 16-leaf tree). Contiguous ascending pairing + strict '>'
                // == numpy argmax first-occurrence tie-break, exact f32.
                float gv[16]; int gi[16];
                #pragma unroll
                for (int g = 0; g < 16; ++g) {
                    const float4 fq = *reinterpret_cast<const float4*>(&fv[g * 4]);
                    const float c0 = fq.x + w[4*g+0];
                    const float c1 = fq.y + w[4*g+1];
                    const float c2 = fq.z + w[4*g+2];
                    const float c3 = fq.w + w[4*g+3];
                    const bool g01 = c1 > c0;
                    const float v01 = g01 ? c1 : c0; const int i01 = g01 ? (4*g+1) : (4*g+0);
                    const bool g23 = c3 > c2;
                    const float v23 = g23 ? c3 : c2; const int i23 = g23 ? (4*g+3) : (4*g+2);
                    const bool gg = v23 > v01;
                    gv[g] = gg ? v23 : v01; gi[g] = gg ? i23 : i01;
                }
                #pragma unroll
                for (int n = 8; n >= 1; n >>= 1) {
                    #pragma unroll
                    for (int k = 0; k < n; ++k) {
                        const bool g = gv[2*k+1] > gv[2*k];
                        gv[k] = g ? gv[2*k+1] : gv[2*k];
                        gi[k] = g ? gi[2*k+1] : gi[2*k];
                    }
                }
                nf = gv[0] + cur[i];              // emission added after max
                fv[lane] = nf;                    // ds_write_b32 (in-order vs
                bptr[t * TAGS + lane] = (unsigned char)gi[0]; // next step's reads)
                __builtin_amdgcn_wave_barrier();  // sched fence, no code
            }
        }
        #pragma unroll
        for (int i = 0; i < PF; ++i) cur[i] = nxt[i];
    }

    // terminal = fv + W[END][prev]; first-max argmax via shuffle butterfly
    float tv = nf + wEnd;
    int   ti = lane;
    #pragma unroll
    for (int off = 32; off >= 1; off >>= 1) {
        const float ov = __shfl_xor(tv, off);
        const int   oi = __shfl_xor(ti, off);
        if (ov > tv || (ov == tv && oi < ti)) { tv = ov; ti = oi; }
    }
    if (lane == 0) out[b] = tv;
    const int bestlast = ti;                      // uniform across lanes

    // padding region: path[t] = bestlast for t in [len-1, T)
    for (int t = lane; t < T; t += 64)
        if (t >= len - 1) path[t] = (unsigned short)bestlast;
    __builtin_amdgcn_wave_barrier();

    // serial chase (lane 0, LDS-resident backpointers; broadcast-free reads)
    if (lane == 0) {
        int tag = bestlast;
        for (int t = len - 1; t >= 1; --t) {
            tag = bptr[t * TAGS + tag];
            path[t - 1] = (unsigned short)tag;
        }
    }
    __builtin_amdgcn_wave_barrier();

    // coalesced path writeback (tags as float32)
    float* pout = out + B + (size_t)b * T;
    for (int t = lane; t < T; t += 64)
        pout[t] = (float)path[t];
}

extern "C" void kernel_launch(void* const* d_in, const int* in_sizes, int n_in,
                              void* d_out, int out_size, void* d_ws, size_t ws_size,
                              hipStream_t stream) {
    const float* feats   = (const float*)d_in[0];
    const float* weights = (const float*)d_in[1];
    const int*   lens    = (const int*)d_in[2];
    float*       out     = (float*)d_out;

    const int B = in_sizes[2];
    const int T = in_sizes[0] / (B * TAGS);

    crf_viterbi<<<dim3(B), dim3(64), 0, stream>>>(feats, weights, lens, out, B, T);
}

// Round 3
// 435.206 us; speedup vs baseline: 7.5067x; 2.3004x over previous
//
#include <hip/hip_runtime.h>

#define TAGS 64
#define MAXT 512
#define NEG  -10000.0f
#define CH   8   // feat-staging chunk: steps per LDS buffer

// One wave (64 lanes) per batch. lane = "next" tag. Single-wave block: no
// barriers at all — same-wave LDS ops are in program order, so the per-step
// fv write -> read dependency and the fbuf staging are ordered for free.
// feats are staged global -> regs -> LDS in 8-step chunks, issued one full
// chunk ahead, so the per-step emission read is a conflict-free ds_read_b32
// and no step ever waits on global memory (round-2 profile showed ~3000
// cyc/step of exposed global latency from the register-prefetch scheme).
__global__ __launch_bounds__(64, 1) void crf_viterbi(
    const float* __restrict__ feats,   // [B, T, K]
    const float* __restrict__ weights, // [K, K] (weights[next][prev])
    const int*   __restrict__ lens,    // [B]
    float*       __restrict__ out,     // [B] scores ++ [B*T] paths (as f32)
    int B, int T)
{
    const int b    = blockIdx.x;
    const int lane = threadIdx.x;              // next tag
    const int len  = lens[b];                  // 1..T

    __shared__ float fv[TAGS];
    __shared__ float fbuf[2][CH * TAGS];       // 2 x 2 KB feat staging
    __shared__ unsigned char  bptr[MAXT * TAGS];
    __shared__ unsigned short path[MAXT];
    // total LDS ~38.1 KB -> 4 blocks/CU (<= 40960 B)

    // W row for this lane -> 64 VGPRs, reused every step
    float w[TAGS];
    #pragma unroll
    for (int i = 0; i < 16; ++i) {
        const float4 v = *reinterpret_cast<const float4*>(weights + lane * TAGS + i * 4);
        w[4*i+0] = v.x; w[4*i+1] = v.y; w[4*i+2] = v.z; w[4*i+3] = v.w;
    }
    const float wEnd = weights[1 * TAGS + lane];  // transition into END

    fv[lane] = (lane == 0) ? 0.0f : NEG;          // START = 0

    const float* fb  = feats + (size_t)b * T * TAGS;
    const int    lim = len * TAGS - 4;            // clamp for tail-chunk loads

    // one step of the recurrence; feat read issued first so its latency
    // overlaps the fv reads + tree
    float nf = NEG;
    auto step = [&](int cbuf, int i, int t) {
        const float feat = fbuf[cbuf][i * TAGS + lane];  // ds_read_b32, 2-way = free
        // grouped add+argmax over 64 prev tags; contiguous ascending pairing
        // + strict '>' == numpy first-occurrence argmax, exact f32
        float gv[16]; int gi[16];
        #pragma unroll
        for (int g = 0; g < 16; ++g) {
            const float4 fq = *reinterpret_cast<const float4*>(&fv[g * 4]);
            const float c0 = fq.x + w[4*g+0];
            const float c1 = fq.y + w[4*g+1];
            const float c2 = fq.z + w[4*g+2];
            const float c3 = fq.w + w[4*g+3];
            const bool g01 = c1 > c0;
            const float v01 = g01 ? c1 : c0; const int i01 = g01 ? (4*g+1) : (4*g+0);
            const bool g23 = c3 > c2;
            const float v23 = g23 ? c3 : c2; const int i23 = g23 ? (4*g+3) : (4*g+2);
            const bool gg = v23 > v01;
            gv[g] = gg ? v23 : v01; gi[g] = gg ? i23 : i01;
        }
        #pragma unroll
        for (int n = 8; n >= 1; n >>= 1) {
            #pragma unroll
            for (int k = 0; k < n; ++k) {
                const bool g = gv[2*k+1] > gv[2*k];
                gv[k] = g ? gv[2*k+1] : gv[2*k];
                gi[k] = g ? gi[2*k+1] : gi[2*k];
            }
        }
        nf = gv[0] + feat;                        // emission added after max
        fv[lane] = nf;
        bptr[t * TAGS + lane] = (unsigned char)gi[0];
    };

    // prologue: stage chunk 0 -> fbuf[0]; issue chunk-1 loads
    {
        int o0 = 4 * lane;        if (o0 > lim) o0 = lim;
        int o1 = 256 + 4 * lane;  if (o1 > lim) o1 = lim;
        const float4 r0 = *reinterpret_cast<const float4*>(fb + o0);
        const float4 r1 = *reinterpret_cast<const float4*>(fb + o1);
        *reinterpret_cast<float4*>(&fbuf[0][4 * lane])       = r0;
        *reinterpret_cast<float4*>(&fbuf[0][256 + 4 * lane]) = r1;
    }
    float4 n0, n1;
    {
        int o0 = CH * TAGS + 4 * lane;        if (o0 > lim) o0 = lim;
        int o1 = CH * TAGS + 256 + 4 * lane;  if (o1 > lim) o1 = lim;
        n0 = *reinterpret_cast<const float4*>(fb + o0);
        n1 = *reinterpret_cast<const float4*>(fb + o1);
    }

    int cb = 0;
    const int nfull = len / CH;
    for (int c = 0; c < nfull; ++c) {
        #pragma unroll
        for (int i = 0; i < CH; ++i) step(cb, i, c * CH + i);
        // stage chunk c+1 (loads landed ~8 steps ago), issue chunk c+2
        *reinterpret_cast<float4*>(&fbuf[cb ^ 1][4 * lane])       = n0;
        *reinterpret_cast<float4*>(&fbuf[cb ^ 1][256 + 4 * lane]) = n1;
        {
            int o0 = (c + 2) * CH * TAGS + 4 * lane;        if (o0 > lim) o0 = lim;
            int o1 = (c + 2) * CH * TAGS + 256 + 4 * lane;  if (o1 > lim) o1 = lim;
            n0 = *reinterpret_cast<const float4*>(fb + o0);
            n1 = *reinterpret_cast<const float4*>(fb + o1);
        }
        cb ^= 1;
    }
    const int rem = len - nfull * CH;             // 0..7 remainder steps
    for (int i = 0; i < rem; ++i) step(cb, i, nfull * CH + i);

    // terminal = fv + W[END][prev]; first-max argmax via shuffle butterfly
    float tv = nf + wEnd;
    int   ti = lane;
    #pragma unroll
    for (int off = 32; off >= 1; off >>= 1) {
        const float ov = __shfl_xor(tv, off);
        const int   oi = __shfl_xor(ti, off);
        if (ov > tv || (ov == tv && oi < ti)) { tv = ov; ti = oi; }
    }
    if (lane == 0) out[b] = tv;
    const int bestlast = ti;                      // uniform across lanes

    // padding region: path[t] = bestlast for t in [len-1, T)
    for (int t = lane; t < T; t += 64)
        if (t >= len - 1) path[t] = (unsigned short)bestlast;
    __builtin_amdgcn_wave_barrier();

    // serial chase (lane 0, LDS-resident backpointers)
    if (lane == 0) {
        int tag = bestlast;
        for (int t = len - 1; t >= 1; --t) {
            tag = bptr[t * TAGS + tag];
            path[t - 1] = (unsigned short)tag;
        }
    }
    __builtin_amdgcn_wave_barrier();

    // coalesced path writeback (tags as float32)
    float* pout = out + B + (size_t)b * T;
    for (int t = lane; t < T; t += 64)
        pout[t] = (float)path[t];
}

extern "C" void kernel_launch(void* const* d_in, const int* in_sizes, int n_in,
                              void* d_out, int out_size, void* d_ws, size_t ws_size,
                              hipStream_t stream) {
    const float* feats   = (const float*)d_in[0];
    const float* weights = (const float*)d_in[1];
    const int*   lens    = (const int*)d_in[2];
    float*       out     = (float*)d_out;

    const int B = in_sizes[2];
    const int T = in_sizes[0] / (B * TAGS);

    crf_viterbi<<<dim3(B), dim3(64), 0, stream>>>(feats, weights, lens, out, B, T);
}